// Round 1
// baseline (2157.874 us; speedup 1.0000x reference)
//
#include <hip/hip_runtime.h>

// GIN 2-layer, eval mode. Linearity trick: transform-then-aggregate.
//   y1 = x@W1a;  pre1 = y1 + segsum(y1[src]*w) + b1a
//   t1 = relu(bn1(pre1)); h1 = relu(t1@W1b + b1b); y2 = h1@W2a  (y2 lives in d_out)
//   pre2 = y2 + segsum(y2[src]*w) + b2a
//   t2 = relu(bn2(pre2)); out = t2@W2b + b2b   (in-place on d_out)

#define BN_EPS 1e-5f

// ---------------- Kernel 1: y1[N,32] = x[N,128] @ W1a[128,32] ----------------
__global__ __launch_bounds__(256) void gemm1_kernel(const float* __restrict__ x,
                                                    const float* __restrict__ W,
                                                    float* __restrict__ y, int N) {
    __shared__ float xs[32][129];     // +1 pad -> conflict-free broadcast reads
    __shared__ float ws[128 * 32];
    int t = threadIdx.x;
    for (int i = t; i < 4096; i += 256) ws[i] = W[i];
    int row0 = blockIdx.x * 32;
    // cooperative coalesced load of 32 rows x 128 floats (4 float4 per thread)
    for (int j = 0; j < 4; ++j) {
        int f4 = t + j * 256;            // 0..1023 float4 slots
        int r  = f4 >> 5;                // 32 float4 per row
        int kc = (f4 & 31) << 2;
        if (row0 + r < N) {
            float4 v = *(const float4*)&x[(size_t)(row0 + r) * 128 + kc];
            xs[r][kc + 0] = v.x; xs[r][kc + 1] = v.y;
            xs[r][kc + 2] = v.z; xs[r][kc + 3] = v.w;
        }
    }
    __syncthreads();
    int r  = t >> 3;                 // 8 threads per row
    int c0 = (t & 7) << 2;           // 4 cols each
    if (row0 + r >= N) return;
    float a0 = 0.f, a1 = 0.f, a2 = 0.f, a3 = 0.f;
    #pragma unroll 8
    for (int k = 0; k < 128; ++k) {
        float xv = xs[r][k];
        const float* wr = &ws[k * 32 + c0];
        a0 += xv * wr[0]; a1 += xv * wr[1]; a2 += xv * wr[2]; a3 += xv * wr[3];
    }
    float4 o = {a0, a1, a2, a3};
    *(float4*)&y[(size_t)(row0 + r) * 32 + c0] = o;
}

// ------------- Kernel 2/4: agg[dst] += y[src]*w  (C channels, C/4 thr/edge) -------------
template <int C>
__global__ __launch_bounds__(256) void scatter_kernel(const int* __restrict__ ei,
                                                      const float* __restrict__ ew,
                                                      const float* __restrict__ y,
                                                      float* __restrict__ agg, int E) {
    constexpr int SH = (C == 32) ? 3 : 4;   // log2(C/4)
    constexpr int TPE = C / 4;
    unsigned gid = blockIdx.x * 256u + threadIdx.x;
    unsigned e = gid >> SH;
    if (e >= (unsigned)E) return;
    int p = (gid & (TPE - 1)) << 2;
    int s = ei[e];
    int d = ei[(size_t)E + e];
    float w = ew[e];
    float4 v = *(const float4*)&y[(size_t)s * C + p];
    float* a = &agg[(size_t)d * C + p];
    atomicAdd(a + 0, v.x * w);
    atomicAdd(a + 1, v.y * w);
    atomicAdd(a + 2, v.z * w);
    atomicAdd(a + 3, v.w * w);
}

// ------- Kernel 3: per-node  t1=relu(bn(y1+agg1+b1a)); h1=relu(t1@W1b+b1b); y2=h1@W2a -------
__global__ __launch_bounds__(256) void mlp1_kernel(const float* __restrict__ y1,
                                                   const float* __restrict__ agg1,
                                                   const float* __restrict__ b1a,
                                                   const float* __restrict__ g1,
                                                   const float* __restrict__ be1,
                                                   const float* __restrict__ m1,
                                                   const float* __restrict__ v1,
                                                   const float* __restrict__ W1b,
                                                   const float* __restrict__ b1b,
                                                   const float* __restrict__ W2a,
                                                   float* __restrict__ y2, int N) {
    __shared__ float w1b[32 * 32];
    __shared__ float w2a[32 * 64];
    __shared__ float t1s[4][32];
    __shared__ float h1s[4][32];
    int t = threadIdx.x;
    for (int i = t; i < 1024; i += 256) w1b[i] = W1b[i];
    for (int i = t; i < 2048; i += 256) w2a[i] = W2a[i];
    int wid = t >> 6, lane = t & 63;
    int node = blockIdx.x * 4 + wid;
    bool act = node < N;
    __syncthreads();
    if (act && lane < 32) {
        int c = lane;
        float pre = y1[(size_t)node * 32 + c] + agg1[(size_t)node * 32 + c] + b1a[c];
        float scale = g1[c] * rsqrtf(v1[c] + BN_EPS);
        t1s[wid][c] = fmaxf((pre - m1[c]) * scale + be1[c], 0.f);
    }
    __syncthreads();
    if (act && lane < 32) {
        int col = lane;
        float acc = b1b[col];
        #pragma unroll
        for (int k = 0; k < 32; ++k) acc += t1s[wid][k] * w1b[k * 32 + col];
        h1s[wid][col] = fmaxf(acc, 0.f);
    }
    __syncthreads();
    if (act) {
        int col = lane;   // 0..63
        float acc = 0.f;
        #pragma unroll
        for (int k = 0; k < 32; ++k) acc += h1s[wid][k] * w2a[k * 64 + col];
        y2[(size_t)node * 64 + col] = acc;
    }
}

// ------- Kernel 5: in-place  t2=relu(bn(y2+agg2+b2a)); out=t2@W2b+b2b -------
__global__ __launch_bounds__(256) void final_kernel(const float* __restrict__ agg2,
                                                    const float* __restrict__ b2a,
                                                    const float* __restrict__ g2,
                                                    const float* __restrict__ be2,
                                                    const float* __restrict__ m2,
                                                    const float* __restrict__ v2,
                                                    const float* __restrict__ W2b,
                                                    const float* __restrict__ b2b,
                                                    float* __restrict__ out, int N) {
    __shared__ float w2b[64 * 64];
    __shared__ float t2s[4][64];
    int t = threadIdx.x;
    for (int i = t; i < 4096; i += 256) w2b[i] = W2b[i];
    int wid = t >> 6, lane = t & 63;
    int node = blockIdx.x * 4 + wid;
    bool act = node < N;
    __syncthreads();
    if (act) {
        int c = lane;
        float pre = out[(size_t)node * 64 + c] + agg2[(size_t)node * 64 + c] + b2a[c];
        float scale = g2[c] * rsqrtf(v2[c] + BN_EPS);
        t2s[wid][c] = fmaxf((pre - m2[c]) * scale + be2[c], 0.f);
    }
    __syncthreads();
    if (act) {
        int col = lane;
        float acc = b2b[col];
        #pragma unroll
        for (int k = 0; k < 64; ++k) acc += t2s[wid][k] * w2b[k * 64 + col];
        out[(size_t)node * 64 + col] = acc;
    }
}

extern "C" void kernel_launch(void* const* d_in, const int* in_sizes, int n_in,
                              void* d_out, int out_size, void* d_ws, size_t ws_size,
                              hipStream_t stream) {
    const float* x   = (const float*)d_in[0];
    const float* ew  = (const float*)d_in[1];
    const float* W1a = (const float*)d_in[2];
    const float* b1a = (const float*)d_in[3];
    const float* g1  = (const float*)d_in[4];
    const float* be1 = (const float*)d_in[5];
    const float* m1  = (const float*)d_in[6];
    const float* v1  = (const float*)d_in[7];
    const float* W1b = (const float*)d_in[8];
    const float* b1b = (const float*)d_in[9];
    const float* W2a = (const float*)d_in[10];
    const float* b2a = (const float*)d_in[11];
    const float* g2  = (const float*)d_in[12];
    const float* be2 = (const float*)d_in[13];
    const float* m2  = (const float*)d_in[14];
    const float* v2  = (const float*)d_in[15];
    const float* W2b = (const float*)d_in[16];
    const float* b2b = (const float*)d_in[17];
    const int*   ei  = (const int*)d_in[18];

    const int N = in_sizes[0] / 128;
    const int E = in_sizes[1];

    float* y1   = (float*)d_ws;                  // N*32
    float* agg1 = y1 + (size_t)N * 32;           // N*32
    float* agg2 = agg1 + (size_t)N * 32;         // N*64
    float* out  = (float*)d_out;                 // y2 lives here, finished in place

    hipMemsetAsync(agg1, 0, (size_t)N * 32 * sizeof(float), stream);
    hipMemsetAsync(agg2, 0, (size_t)N * 64 * sizeof(float), stream);

    gemm1_kernel<<<(N + 31) / 32, 256, 0, stream>>>(x, W1a, y1, N);
    scatter_kernel<32><<<(int)(((size_t)E * 8 + 255) / 256), 256, 0, stream>>>(ei, ew, y1, agg1, E);
    mlp1_kernel<<<(N + 3) / 4, 256, 0, stream>>>(y1, agg1, b1a, g1, be1, m1, v1, W1b, b1b, W2a, out, N);
    scatter_kernel<64><<<(int)(((size_t)E * 16 + 255) / 256), 256, 0, stream>>>(ei, ew, out, agg2, E);
    final_kernel<<<(N + 3) / 4, 256, 0, stream>>>(agg2, b2a, g2, be2, m2, v2, W2b, b2b, out, N);
}

// Round 2
// 567.389 us; speedup vs baseline: 3.8032x; 3.8032x over previous
//
#include <hip/hip_runtime.h>

// GIN 2-layer, eval mode. Transform-then-aggregate (both layers 32-wide):
//   y1 = x@W1a
//   pre1 = y1 + gather(y1) + b1a ; t1 = relu(bn1(pre1)) ; h1 = relu(t1@W1b+b1b)
//   s1  = h1 + gather(h1)        ; pre2 = s1@W2a + b2a  ; t2 = relu(bn2(pre2))
//   out = t2@W2b + b2b
// Aggregation via per-call CSR build (deg -> scan -> fill), gather with zero
// float atomics.

#define BN_EPS 1e-5f

// ---------------- K1: y1[N,32] = x[N,128] @ W1a[128,32] ----------------
__global__ __launch_bounds__(256) void gemm1_kernel(const float* __restrict__ x,
                                                    const float* __restrict__ W,
                                                    float* __restrict__ y, int N) {
    __shared__ float xs[32][129];
    __shared__ float ws[128 * 32];
    int t = threadIdx.x;
    for (int i = t; i < 4096; i += 256) ws[i] = W[i];
    int row0 = blockIdx.x * 32;
    for (int j = 0; j < 4; ++j) {
        int f4 = t + j * 256;
        int r  = f4 >> 5;
        int kc = (f4 & 31) << 2;
        if (row0 + r < N) {
            float4 v = *(const float4*)&x[(size_t)(row0 + r) * 128 + kc];
            xs[r][kc + 0] = v.x; xs[r][kc + 1] = v.y;
            xs[r][kc + 2] = v.z; xs[r][kc + 3] = v.w;
        }
    }
    __syncthreads();
    int r  = t >> 3;
    int c0 = (t & 7) << 2;
    if (row0 + r >= N) return;
    float a0 = 0.f, a1 = 0.f, a2 = 0.f, a3 = 0.f;
    #pragma unroll 8
    for (int k = 0; k < 128; ++k) {
        float xv = xs[r][k];
        const float* wr = &ws[k * 32 + c0];
        a0 += xv * wr[0]; a1 += xv * wr[1]; a2 += xv * wr[2]; a3 += xv * wr[3];
    }
    float4 o = {a0, a1, a2, a3};
    *(float4*)&y[(size_t)(row0 + r) * 32 + c0] = o;
}

// ---------------- K2: degree histogram over dst ----------------
__global__ __launch_bounds__(256) void deg_kernel(const int* __restrict__ ei,
                                                  int* __restrict__ deg, int E) {
    int e = blockIdx.x * 256 + threadIdx.x;
    if (e < E) atomicAdd(&deg[ei[(size_t)E + e]], 1);
}

// ---------------- K3: single-block exclusive scan -> row_ptr, cursor ----------------
__global__ __launch_bounds__(1024) void scan_kernel(const int* __restrict__ deg,
                                                    int* __restrict__ row_ptr,
                                                    int* __restrict__ cursor, int N) {
    __shared__ int ps[1024];
    int t = threadIdx.x;
    int chunk = (N + 1023) >> 10;
    int lo = t * chunk;
    int hi = min(lo + chunk, N);
    int s = 0;
    for (int i = lo; i < hi; ++i) s += deg[i];
    ps[t] = s;
    __syncthreads();
    for (int off = 1; off < 1024; off <<= 1) {
        int v = (t >= off) ? ps[t - off] : 0;
        __syncthreads();
        ps[t] += v;
        __syncthreads();
    }
    int base = (t == 0) ? 0 : ps[t - 1];
    for (int i = lo; i < hi; ++i) {
        row_ptr[i] = base;
        cursor[i]  = base;
        base += deg[i];
    }
    if (t == 0) row_ptr[N] = ps[1023];
}

// ---------------- K4: fill CSR (src, weight) packed as int2 ----------------
__global__ __launch_bounds__(256) void fill_kernel(const int* __restrict__ ei,
                                                   const float* __restrict__ ew,
                                                   int* __restrict__ cursor,
                                                   int2* __restrict__ epack, int E) {
    int e = blockIdx.x * 256 + threadIdx.x;
    if (e >= E) return;
    int s = ei[e];
    int d = ei[(size_t)E + e];
    int pos = atomicAdd(&cursor[d], 1);
    epack[pos] = make_int2(s, __float_as_int(ew[e]));
}

// ------- K5: gather(y1) + BN + ReLU + @W1b + ReLU -> h1   (32 nodes/block, 8 thr/node) -------
__global__ __launch_bounds__(256) void layer1_kernel(
    const float* __restrict__ y1, const int* __restrict__ row_ptr,
    const int2* __restrict__ epack,
    const float* __restrict__ b1a, const float* __restrict__ g1,
    const float* __restrict__ be1, const float* __restrict__ m1,
    const float* __restrict__ v1, const float* __restrict__ W1b,
    const float* __restrict__ b1b, float* __restrict__ h1, int N) {
    __shared__ float w1b[1024];
    __shared__ float t1s[32][33];
    int t = threadIdx.x;
    for (int i = t; i < 1024; i += 256) w1b[i] = W1b[i];
    int g = t >> 3, l = t & 7;
    int node = blockIdx.x * 32 + g;
    int c0 = l << 2;
    bool act = node < N;
    float4 acc = {0.f, 0.f, 0.f, 0.f};
    int beg = 0, end = 0;
    if (act) { beg = row_ptr[node]; end = row_ptr[node + 1]; }
    for (int e = beg; e < end; ++e) {
        int2 p = epack[e];
        float w = __int_as_float(p.y);
        float4 v = *(const float4*)&y1[(size_t)p.x * 32 + c0];
        acc.x += v.x * w; acc.y += v.y * w; acc.z += v.z * w; acc.w += v.w * w;
    }
    if (act) {
        float4 self = *(const float4*)&y1[(size_t)node * 32 + c0];
        float pr[4] = {self.x + acc.x, self.y + acc.y, self.z + acc.z, self.w + acc.w};
        #pragma unroll
        for (int j = 0; j < 4; ++j) {
            int c = c0 + j;
            float scale = g1[c] * rsqrtf(v1[c] + BN_EPS);
            t1s[g][c] = fmaxf((pr[j] + b1a[c] - m1[c]) * scale + be1[c], 0.f);
        }
    }
    __syncthreads();
    if (act) {
        float a0 = b1b[c0 + 0], a1 = b1b[c0 + 1], a2 = b1b[c0 + 2], a3 = b1b[c0 + 3];
        #pragma unroll
        for (int k = 0; k < 32; ++k) {
            float tv = t1s[g][k];
            const float* wr = &w1b[k * 32 + c0];
            a0 += tv * wr[0]; a1 += tv * wr[1]; a2 += tv * wr[2]; a3 += tv * wr[3];
        }
        float4 o = {fmaxf(a0, 0.f), fmaxf(a1, 0.f), fmaxf(a2, 0.f), fmaxf(a3, 0.f)};
        *(float4*)&h1[(size_t)node * 32 + c0] = o;
    }
}

// ------- K6: gather(h1) -> s1 ; @W2a + BN + ReLU ; @W2b + b2b -> out -------
__global__ __launch_bounds__(256) void layer2_kernel(
    const float* __restrict__ h1, const int* __restrict__ row_ptr,
    const int2* __restrict__ epack,
    const float* __restrict__ W2a, const float* __restrict__ b2a,
    const float* __restrict__ g2, const float* __restrict__ be2,
    const float* __restrict__ m2, const float* __restrict__ v2,
    const float* __restrict__ W2b, const float* __restrict__ b2b,
    float* __restrict__ out, int N) {
    __shared__ float w2a[2048];
    __shared__ float w2b[4096];
    __shared__ float s1s[32][33];
    __shared__ float t2s[32][65];
    int t = threadIdx.x;
    for (int i = t; i < 2048; i += 256) w2a[i] = W2a[i];
    for (int i = t; i < 4096; i += 256) w2b[i] = W2b[i];
    int g = t >> 3, l = t & 7;
    int node = blockIdx.x * 32 + g;
    int c0 = l << 2;
    bool act = node < N;
    float4 acc = {0.f, 0.f, 0.f, 0.f};
    int beg = 0, end = 0;
    if (act) { beg = row_ptr[node]; end = row_ptr[node + 1]; }
    for (int e = beg; e < end; ++e) {
        int2 p = epack[e];
        float w = __int_as_float(p.y);
        float4 v = *(const float4*)&h1[(size_t)p.x * 32 + c0];
        acc.x += v.x * w; acc.y += v.y * w; acc.z += v.z * w; acc.w += v.w * w;
    }
    if (act) {
        float4 self = *(const float4*)&h1[(size_t)node * 32 + c0];
        s1s[g][c0 + 0] = self.x + acc.x;
        s1s[g][c0 + 1] = self.y + acc.y;
        s1s[g][c0 + 2] = self.z + acc.z;
        s1s[g][c0 + 3] = self.w + acc.w;
    }
    __syncthreads();
    int d0 = l << 3;
    if (act) {
        float a[8];
        #pragma unroll
        for (int j = 0; j < 8; ++j) a[j] = b2a[d0 + j];
        #pragma unroll
        for (int k = 0; k < 32; ++k) {
            float sv = s1s[g][k];
            const float* wr = &w2a[k * 64 + d0];
            #pragma unroll
            for (int j = 0; j < 8; ++j) a[j] += sv * wr[j];
        }
        #pragma unroll
        for (int j = 0; j < 8; ++j) {
            int c = d0 + j;
            float scale = g2[c] * rsqrtf(v2[c] + BN_EPS);
            t2s[g][c] = fmaxf((a[j] - m2[c]) * scale + be2[c], 0.f);
        }
    }
    __syncthreads();
    if (act) {
        float a[8];
        #pragma unroll
        for (int j = 0; j < 8; ++j) a[j] = b2b[d0 + j];
        #pragma unroll
        for (int k = 0; k < 64; ++k) {
            float tv = t2s[g][k];
            const float* wr = &w2b[k * 64 + d0];
            #pragma unroll
            for (int j = 0; j < 8; ++j) a[j] += tv * wr[j];
        }
        float4 o0 = {a[0], a[1], a[2], a[3]};
        float4 o1 = {a[4], a[5], a[6], a[7]};
        *(float4*)&out[(size_t)node * 64 + d0 + 0] = o0;
        *(float4*)&out[(size_t)node * 64 + d0 + 4] = o1;
    }
}

extern "C" void kernel_launch(void* const* d_in, const int* in_sizes, int n_in,
                              void* d_out, int out_size, void* d_ws, size_t ws_size,
                              hipStream_t stream) {
    const float* x   = (const float*)d_in[0];
    const float* ew  = (const float*)d_in[1];
    const float* W1a = (const float*)d_in[2];
    const float* b1a = (const float*)d_in[3];
    const float* g1  = (const float*)d_in[4];
    const float* be1 = (const float*)d_in[5];
    const float* m1  = (const float*)d_in[6];
    const float* v1  = (const float*)d_in[7];
    const float* W1b = (const float*)d_in[8];
    const float* b1b = (const float*)d_in[9];
    const float* W2a = (const float*)d_in[10];
    const float* b2a = (const float*)d_in[11];
    const float* g2  = (const float*)d_in[12];
    const float* be2 = (const float*)d_in[13];
    const float* m2  = (const float*)d_in[14];
    const float* v2  = (const float*)d_in[15];
    const float* W2b = (const float*)d_in[16];
    const float* b2b = (const float*)d_in[17];
    const int*   ei  = (const int*)d_in[18];

    const int N = in_sizes[0] / 128;
    const int E = in_sizes[1];

    // workspace layout (8B-aligned epack first)
    int2*  epack   = (int2*)d_ws;                         // E int2
    float* y1      = (float*)(epack + E);                 // N*32
    float* h1      = y1 + (size_t)N * 32;                 // N*32
    int*   deg     = (int*)(h1 + (size_t)N * 32);         // N
    int*   row_ptr = deg + N;                             // N+1
    int*   cursor  = row_ptr + N + 1;                     // N

    hipMemsetAsync(deg, 0, (size_t)N * sizeof(int), stream);

    gemm1_kernel<<<(N + 31) / 32, 256, 0, stream>>>(x, W1a, y1, N);
    deg_kernel<<<(E + 255) / 256, 256, 0, stream>>>(ei, deg, E);
    scan_kernel<<<1, 1024, 0, stream>>>(deg, row_ptr, cursor, N);
    fill_kernel<<<(E + 255) / 256, 256, 0, stream>>>(ei, ew, cursor, epack, E);
    layer1_kernel<<<(N + 31) / 32, 256, 0, stream>>>(y1, row_ptr, epack,
                                                     b1a, g1, be1, m1, v1, W1b, b1b, h1, N);
    layer2_kernel<<<(N + 31) / 32, 256, 0, stream>>>(h1, row_ptr, epack,
                                                     W2a, b2a, g2, be2, m2, v2, W2b, b2b,
                                                     (float*)d_out, N);
}

// Round 3
// 356.519 us; speedup vs baseline: 6.0526x; 1.5915x over previous
//
#include <hip/hip_runtime.h>

// GIN 2-layer, eval mode. Transform-then-aggregate (both layers 32-wide):
//   y1 = x@W1a
//   pre1 = y1 + gather(y1) + b1a ; t1 = relu(bn1(pre1)) ; h1 = relu(t1@W1b+b1b)
//   s1  = h1 + gather(h1)        ; pre2 = s1@W2a + b2a  ; t2 = relu(bn2(pre2))
//   out = t2@W2b + b2b
// CSR built per call: deg -> two-level scan -> fill. Zero float atomics.

#define BN_EPS 1e-5f

// ---------------- K1: y1[N,32] = x[N,128] @ W1a[128,32] ----------------
__global__ __launch_bounds__(256) void gemm1_kernel(const float* __restrict__ x,
                                                    const float* __restrict__ W,
                                                    float* __restrict__ y, int N) {
    __shared__ float xs[32][129];
    __shared__ float ws[128 * 32];
    int t = threadIdx.x;
    for (int i = t; i < 4096; i += 256) ws[i] = W[i];
    int row0 = blockIdx.x * 32;
    for (int j = 0; j < 4; ++j) {
        int f4 = t + j * 256;
        int r  = f4 >> 5;
        int kc = (f4 & 31) << 2;
        if (row0 + r < N) {
            float4 v = *(const float4*)&x[(size_t)(row0 + r) * 128 + kc];
            xs[r][kc + 0] = v.x; xs[r][kc + 1] = v.y;
            xs[r][kc + 2] = v.z; xs[r][kc + 3] = v.w;
        }
    }
    __syncthreads();
    int r  = t >> 3;
    int c0 = (t & 7) << 2;
    if (row0 + r >= N) return;
    float a0 = 0.f, a1 = 0.f, a2 = 0.f, a3 = 0.f;
    #pragma unroll 8
    for (int k = 0; k < 128; ++k) {
        float xv = xs[r][k];
        const float* wr = &ws[k * 32 + c0];
        a0 += xv * wr[0]; a1 += xv * wr[1]; a2 += xv * wr[2]; a3 += xv * wr[3];
    }
    float4 o = {a0, a1, a2, a3};
    *(float4*)&y[(size_t)(row0 + r) * 32 + c0] = o;
}

// ---------------- K2: degree histogram over dst ----------------
__global__ __launch_bounds__(256) void deg_kernel(const int* __restrict__ ei,
                                                  int* __restrict__ deg, int E) {
    int e = blockIdx.x * 256 + threadIdx.x;
    if (e < E) atomicAdd(&deg[ei[(size_t)E + e]], 1);
}

// ---------------- K3a: per-block local exclusive scan (1024-elem tiles) ----------------
__global__ __launch_bounds__(256) void scan_a_kernel(const int* __restrict__ deg,
                                                     int* __restrict__ loc,
                                                     int* __restrict__ bsum, int N) {
    __shared__ int ps[256];
    int t = threadIdx.x;
    int base = blockIdx.x * 1024 + t * 4;
    int v[4];
    #pragma unroll
    for (int j = 0; j < 4; ++j) v[j] = (base + j < N) ? deg[base + j] : 0;
    int s = v[0] + v[1] + v[2] + v[3];
    ps[t] = s;
    __syncthreads();
    for (int off = 1; off < 256; off <<= 1) {
        int x = (t >= off) ? ps[t - off] : 0;
        __syncthreads();
        ps[t] += x;
        __syncthreads();
    }
    int excl = ps[t] - s;
    #pragma unroll
    for (int j = 0; j < 4; ++j) {
        if (base + j < N) loc[base + j] = excl;
        excl += v[j];
    }
    if (t == 255) bsum[blockIdx.x] = ps[255];
}

// ---------------- K3b: 1-block scan of block sums (NB <= 256) ----------------
__global__ __launch_bounds__(256) void scan_b_kernel(const int* __restrict__ bsum,
                                                     int* __restrict__ boff,
                                                     int* __restrict__ row_ptr_last, int NB) {
    __shared__ int ps[256];
    int t = threadIdx.x;
    int s = (t < NB) ? bsum[t] : 0;
    ps[t] = s;
    __syncthreads();
    for (int off = 1; off < 256; off <<= 1) {
        int x = (t >= off) ? ps[t - off] : 0;
        __syncthreads();
        ps[t] += x;
        __syncthreads();
    }
    if (t < NB) boff[t] = ps[t] - s;
    if (t == 255) *row_ptr_last = ps[255];
}

// ---------------- K3c: add block offsets -> row_ptr, cursor ----------------
__global__ __launch_bounds__(256) void scan_c_kernel(const int* __restrict__ loc,
                                                     const int* __restrict__ boff,
                                                     int* __restrict__ row_ptr,
                                                     int* __restrict__ cursor, int N) {
    int t = threadIdx.x;
    int base = blockIdx.x * 1024 + t * 4;
    int b = boff[blockIdx.x];
    #pragma unroll
    for (int j = 0; j < 4; ++j) {
        int i = base + j;
        if (i < N) {
            int v = loc[i] + b;
            row_ptr[i] = v;
            cursor[i]  = v;
        }
    }
}

// ---------------- K4: fill CSR (src, weight) packed as int2 ----------------
__global__ __launch_bounds__(256) void fill_kernel(const int* __restrict__ ei,
                                                   const float* __restrict__ ew,
                                                   int* __restrict__ cursor,
                                                   int2* __restrict__ epack, int E) {
    int e = blockIdx.x * 256 + threadIdx.x;
    if (e >= E) return;
    int s = ei[e];
    int d = ei[(size_t)E + e];
    int pos = atomicAdd(&cursor[d], 1);
    epack[pos] = make_int2(s, __float_as_int(ew[e]));
}

// ------- K5: gather(y1) + BN + ReLU + @W1b + ReLU -> h1   (32 nodes/block, 8 thr/node) -------
__global__ __launch_bounds__(256) void layer1_kernel(
    const float* __restrict__ y1, const int* __restrict__ row_ptr,
    const int2* __restrict__ epack,
    const float* __restrict__ b1a, const float* __restrict__ g1,
    const float* __restrict__ be1, const float* __restrict__ m1,
    const float* __restrict__ v1, const float* __restrict__ W1b,
    const float* __restrict__ b1b, float* __restrict__ h1, int N) {
    __shared__ float w1b[1024];
    __shared__ float t1s[32][33];
    int t = threadIdx.x;
    for (int i = t; i < 1024; i += 256) w1b[i] = W1b[i];
    int g = t >> 3, l = t & 7;
    int node = blockIdx.x * 32 + g;
    int c0 = l << 2;
    bool act = node < N;
    float4 acc = {0.f, 0.f, 0.f, 0.f};
    int beg = 0, end = 0;
    if (act) { beg = row_ptr[node]; end = row_ptr[node + 1]; }
    for (int e = beg; e < end; ++e) {
        int2 p = epack[e];
        float w = __int_as_float(p.y);
        float4 v = *(const float4*)&y1[(size_t)p.x * 32 + c0];
        acc.x += v.x * w; acc.y += v.y * w; acc.z += v.z * w; acc.w += v.w * w;
    }
    if (act) {
        float4 self = *(const float4*)&y1[(size_t)node * 32 + c0];
        float pr[4] = {self.x + acc.x, self.y + acc.y, self.z + acc.z, self.w + acc.w};
        #pragma unroll
        for (int j = 0; j < 4; ++j) {
            int c = c0 + j;
            float scale = g1[c] * rsqrtf(v1[c] + BN_EPS);
            t1s[g][c] = fmaxf((pr[j] + b1a[c] - m1[c]) * scale + be1[c], 0.f);
        }
    }
    __syncthreads();
    if (act) {
        float a0 = b1b[c0 + 0], a1 = b1b[c0 + 1], a2 = b1b[c0 + 2], a3 = b1b[c0 + 3];
        #pragma unroll
        for (int k = 0; k < 32; ++k) {
            float tv = t1s[g][k];
            const float* wr = &w1b[k * 32 + c0];
            a0 += tv * wr[0]; a1 += tv * wr[1]; a2 += tv * wr[2]; a3 += tv * wr[3];
        }
        float4 o = {fmaxf(a0, 0.f), fmaxf(a1, 0.f), fmaxf(a2, 0.f), fmaxf(a3, 0.f)};
        *(float4*)&h1[(size_t)node * 32 + c0] = o;
    }
}

// ------- K6: gather(h1) -> s1 ; @W2a + BN + ReLU ; @W2b + b2b -> out -------
__global__ __launch_bounds__(256) void layer2_kernel(
    const float* __restrict__ h1, const int* __restrict__ row_ptr,
    const int2* __restrict__ epack,
    const float* __restrict__ W2a, const float* __restrict__ b2a,
    const float* __restrict__ g2, const float* __restrict__ be2,
    const float* __restrict__ m2, const float* __restrict__ v2,
    const float* __restrict__ W2b, const float* __restrict__ b2b,
    float* __restrict__ out, int N) {
    __shared__ float w2a[2048];
    __shared__ float w2b[4096];
    __shared__ float s1s[32][33];
    __shared__ float t2s[32][65];
    int t = threadIdx.x;
    for (int i = t; i < 2048; i += 256) w2a[i] = W2a[i];
    for (int i = t; i < 4096; i += 256) w2b[i] = W2b[i];
    int g = t >> 3, l = t & 7;
    int node = blockIdx.x * 32 + g;
    int c0 = l << 2;
    bool act = node < N;
    float4 acc = {0.f, 0.f, 0.f, 0.f};
    int beg = 0, end = 0;
    if (act) { beg = row_ptr[node]; end = row_ptr[node + 1]; }
    for (int e = beg; e < end; ++e) {
        int2 p = epack[e];
        float w = __int_as_float(p.y);
        float4 v = *(const float4*)&h1[(size_t)p.x * 32 + c0];
        acc.x += v.x * w; acc.y += v.y * w; acc.z += v.z * w; acc.w += v.w * w;
    }
    if (act) {
        float4 self = *(const float4*)&h1[(size_t)node * 32 + c0];
        s1s[g][c0 + 0] = self.x + acc.x;
        s1s[g][c0 + 1] = self.y + acc.y;
        s1s[g][c0 + 2] = self.z + acc.z;
        s1s[g][c0 + 3] = self.w + acc.w;
    }
    __syncthreads();
    int d0 = l << 3;
    if (act) {
        float a[8];
        #pragma unroll
        for (int j = 0; j < 8; ++j) a[j] = b2a[d0 + j];
        #pragma unroll
        for (int k = 0; k < 32; ++k) {
            float sv = s1s[g][k];
            const float* wr = &w2a[k * 64 + d0];
            #pragma unroll
            for (int j = 0; j < 8; ++j) a[j] += sv * wr[j];
        }
        #pragma unroll
        for (int j = 0; j < 8; ++j) {
            int c = d0 + j;
            float scale = g2[c] * rsqrtf(v2[c] + BN_EPS);
            t2s[g][c] = fmaxf((a[j] - m2[c]) * scale + be2[c], 0.f);
        }
    }
    __syncthreads();
    if (act) {
        float a[8];
        #pragma unroll
        for (int j = 0; j < 8; ++j) a[j] = b2b[d0 + j];
        #pragma unroll
        for (int k = 0; k < 64; ++k) {
            float tv = t2s[g][k];
            const float* wr = &w2b[k * 64 + d0];
            #pragma unroll
            for (int j = 0; j < 8; ++j) a[j] += tv * wr[j];
        }
        float4 o0 = {a[0], a[1], a[2], a[3]};
        float4 o1 = {a[4], a[5], a[6], a[7]};
        *(float4*)&out[(size_t)node * 64 + d0 + 0] = o0;
        *(float4*)&out[(size_t)node * 64 + d0 + 4] = o1;
    }
}

extern "C" void kernel_launch(void* const* d_in, const int* in_sizes, int n_in,
                              void* d_out, int out_size, void* d_ws, size_t ws_size,
                              hipStream_t stream) {
    const float* x   = (const float*)d_in[0];
    const float* ew  = (const float*)d_in[1];
    const float* W1a = (const float*)d_in[2];
    const float* b1a = (const float*)d_in[3];
    const float* g1  = (const float*)d_in[4];
    const float* be1 = (const float*)d_in[5];
    const float* m1  = (const float*)d_in[6];
    const float* v1  = (const float*)d_in[7];
    const float* W1b = (const float*)d_in[8];
    const float* b1b = (const float*)d_in[9];
    const float* W2a = (const float*)d_in[10];
    const float* b2a = (const float*)d_in[11];
    const float* g2  = (const float*)d_in[12];
    const float* be2 = (const float*)d_in[13];
    const float* m2  = (const float*)d_in[14];
    const float* v2  = (const float*)d_in[15];
    const float* W2b = (const float*)d_in[16];
    const float* b2b = (const float*)d_in[17];
    const int*   ei  = (const int*)d_in[18];

    const int N = in_sizes[0] / 128;
    const int E = in_sizes[1];
    const int NB = (N + 1023) / 1024;   // scan tiles (<= 256)

    // workspace layout (8B-aligned epack first)
    int2*  epack   = (int2*)d_ws;                         // E int2
    float* y1      = (float*)(epack + E);                 // N*32
    float* h1      = y1 + (size_t)N * 32;                 // N*32
    int*   deg     = (int*)(h1 + (size_t)N * 32);         // N
    int*   row_ptr = deg + N;                             // N+1
    int*   cursor  = row_ptr + N + 1;                     // N
    int*   loc     = cursor + N;                          // N
    int*   bsum    = loc + N;                             // NB
    int*   boff    = bsum + 256;                          // NB

    hipMemsetAsync(deg, 0, (size_t)N * sizeof(int), stream);

    gemm1_kernel<<<(N + 31) / 32, 256, 0, stream>>>(x, W1a, y1, N);
    deg_kernel<<<(E + 255) / 256, 256, 0, stream>>>(ei, deg, E);
    scan_a_kernel<<<NB, 256, 0, stream>>>(deg, loc, bsum, N);
    scan_b_kernel<<<1, 256, 0, stream>>>(bsum, boff, &row_ptr[N], NB);
    scan_c_kernel<<<NB, 256, 0, stream>>>(loc, boff, row_ptr, cursor, N);
    fill_kernel<<<(E + 255) / 256, 256, 0, stream>>>(ei, ew, cursor, epack, E);
    layer1_kernel<<<(N + 31) / 32, 256, 0, stream>>>(y1, row_ptr, epack,
                                                     b1a, g1, be1, m1, v1, W1b, b1b, h1, N);
    layer2_kernel<<<(N + 31) / 32, 256, 0, stream>>>(h1, row_ptr, epack,
                                                     W2a, b2a, g2, be2, m2, v2, W2b, b2b,
                                                     (float*)d_out, N);
}